// Round 9
// baseline (171.177 us; speedup 1.0000x reference)
//
#include <hip/hip_runtime.h>
#include <hip/hip_bf16.h>
#include <math.h>

// HarmonicCausalSelfAttention: B=4 T=2048 C=1024 H=16 R=64 D=64, alpha=0.7
// R8 pipeline (4 launches):
//   k_prep : split 8 weight mats to bf16 hi/lo; fold s_r into V-mats, 0.125*log2e into qU
//   k_qkv  : FUSED x->(t)->q,k,v. X staged via global_load_lds (128-col f32 windows,
//            dbuf, 16B-chunk XOR swizzle, pre-swizzled source). Phase-1 split by
//            OUTPUT (wave w: 2 q/k tiles + 1 v tile, full K) -> no f32 partial
//            exchange. Phase-2: in-register hi/lo convert -> Thi/Tlov LDS.
//            Phase-3: per-wave n-quarter (as R7).
//   k_attn : causal flash attn (unchanged from R7): fixed-shift softmax, uniform
//            wave pairing, gll staging w/ pre-swizzled source, XCD swizzle
//   k_cout : FUSED y->(ty)->out, same staged structure (256-col bf16 windows).

#define NB 4
#define NT 2048
#define NC 1024
#define NH 16
#define NR 64
#define ND 64
#define NM (NB * NT)  // 8192

typedef __attribute__((ext_vector_type(8))) short short8;
typedef __attribute__((ext_vector_type(4))) short short4v;
typedef __attribute__((ext_vector_type(4))) float f32x4;
typedef __attribute__((ext_vector_type(4))) float float4v;
typedef __attribute__((ext_vector_type(4))) int int4v;

__device__ __forceinline__ short f2bf(float f) {
    union { __hip_bfloat16 h; short s; } u;
    u.h = __float2bfloat16(f);
    return u.s;
}
__device__ __forceinline__ float bf2f(short s) {
    union { short s; __hip_bfloat16 h; } u;
    u.s = s;
    return __bfloat162float(u.h);
}
__device__ __forceinline__ f32x4 MFMA(short8 a, short8 b, f32x4 c) {
    return __builtin_amdgcn_mfma_f32_16x16x32_bf16(a, b, c, 0, 0, 0);
}
__device__ __forceinline__ float exp2_(float x) {
#if __has_builtin(__builtin_amdgcn_exp2f)
    return __builtin_amdgcn_exp2f(x);
#else
    return exp2f(x);
#endif
}

// async global->LDS, 16B per lane (LDS dest = wave-uniform base + lane*16)
typedef const __attribute__((address_space(1))) unsigned int* gas_ptr;
typedef __attribute__((address_space(3))) unsigned int* las_ptr;
__device__ __forceinline__ void gll16(const void* g, void* l) {
    __builtin_amdgcn_global_load_lds((gas_ptr)g, (las_ptr)l, 16, 0, 0);
}

// ---- weight prep: mats 0-3 = qV,kV,vV,cV ([64][1024], scaled by s_row);
//      mats 4-7 = qU,kU,vU,cU ([1024][64]; qU additionally x 0.125*log2e)
__global__ __launch_bounds__(256) void k_prep(const float* __restrict__ qV, const float* __restrict__ kV,
                                              const float* __restrict__ vV, const float* __restrict__ cV,
                                              const float* __restrict__ qU, const float* __restrict__ kU,
                                              const float* __restrict__ vU, const float* __restrict__ cU,
                                              short* __restrict__ Whi, short* __restrict__ Wlo) {
    const int mat = blockIdx.y;
    const int idx = blockIdx.x * 256 + threadIdx.x;
    const float* src;
    switch (mat) {
        case 0: src = qV; break;
        case 1: src = kV; break;
        case 2: src = vV; break;
        case 3: src = cV; break;
        case 4: src = qU; break;
        case 5: src = kU; break;
        case 6: src = vU; break;
        default: src = cU; break;
    }
    float sc = 1.0f;
    if (mat < 4) sc = powf((float)((idx >> 10) + 1), -0.7f);
    if (mat == 4) sc = 0.125f * 1.44269504088896f;  // fold scale and log2(e)
    const float v = src[idx] * sc;
    const short h = f2bf(v);
    Whi[mat * 65536 + idx] = h;
    Wlo[mat * 65536 + idx] = f2bf(v - bf2f(h));
}

// ---- fused q/k/v: 512 blocks x 16 m-rows, 4 waves.
// Phase1 (split by OUTPUT, full K): wave w -> 2 tiles of q (w<2) or k (w>=2)
//   [tiles (w&1)*2, (w&1)*2+1] + v tile w. X from swizzled LDS windows.
// Phase2: in-register hi/lo convert -> Thi[16][200], Tlov[16][72].
// Phase3: wave w -> n-quarter n0=w*256 (q,k swapped-MFMA packed stores; v 3-term).
__global__ __launch_bounds__(256) void k_qkv(const float* __restrict__ X,
                                             const short* __restrict__ Whi, const short* __restrict__ Wlo,
                                             short* __restrict__ qb, short* __restrict__ kb,
                                             short* __restrict__ vtb) {
    __shared__ __align__(16) char Xl[2][8192];  // [16 rows][128 f32] per buf, swizzled
    __shared__ __align__(16) short Thi[16 * 200];
    __shared__ __align__(16) short Tlov[16 * 72];
    const int tid = threadIdx.x;
    const int w = tid >> 6, l = tid & 63;
    const int lr = l & 15, lk = l >> 4;
    const int mb = blockIdx.x * 16;

    const short* qVh = Whi;
    const short* kVh = Whi + 65536;
    const short* vVh = Whi + 2 * 65536;
    const short* vVl = Wlo + 2 * 65536;
    const short* qUh = Whi + 4 * 65536;
    const short* kUh = Whi + 5 * 65536;
    const short* vUh = Whi + 6 * 65536;
    const short* vUl = Wlo + 6 * 65536;

    // stage one 128-col window: 8KB, 8 gll16 (2 per wave), 2 rows each, coalesced.
    // LDS chunk L holds global logical 16B-chunk (r, lc ^ r)  [lc = L&31, r = L>>5]
    auto stageX = [&](int buf, int win) {
#pragma unroll
        for (int i = 0; i < 2; i++) {
            const int L = (w * 2 + i) * 64 + l;
            const int r = L >> 5, lc = L & 31;
            const int c16 = lc ^ r;
            const float* g = X + (size_t)(mb + r) * NC + win * 128 + c16 * 4;
            gll16(g, Xl[buf] + (w * 2 + i) * 1024);
        }
    };

    // phase-1 weight row pointers for this wave
    const short* Wqk = (w < 2) ? qVh : kVh;
    const int ntA = (w & 1) * 2;
    const short* WA = Wqk + (size_t)(ntA * 16 + lr) * NC;
    const short* WB = Wqk + (size_t)((ntA + 1) * 16 + lr) * NC;
    const short* WvH = vVh + (size_t)(w * 16 + lr) * NC;
    const short* WvL = vVl + (size_t)(w * 16 + lr) * NC;

    f32x4 a0 = 0.0f, a1 = 0.0f, av = 0.0f;
    stageX(0, 0);
    for (int win = 0; win < 8; ++win) {
        const int buf = win & 1;
        __syncthreads();  // drains this window's gll16 + syncs buffers
        if (win < 7) stageX(buf ^ 1, win + 1);
        const char* XB = Xl[buf];
#pragma unroll
        for (int kk = 0; kk < 4; ++kk) {
            const int c16 = kk * 8 + lk * 2;
            const float4v xa = *(const float4v*)(XB + lr * 512 + ((c16 ^ lr) << 4));
            const float4v xb = *(const float4v*)(XB + lr * 512 + (((c16 + 1) ^ lr) << 4));
            float xv[8] = {xa[0], xa[1], xa[2], xa[3], xb[0], xb[1], xb[2], xb[3]};
            short8 xh, xl8;
#pragma unroll
            for (int j = 0; j < 8; j++) {
                const short h = f2bf(xv[j]);
                xh[j] = h;
                xl8[j] = f2bf(xv[j] - bf2f(h));
            }
            const int bo = win * 128 + kk * 32 + lk * 8;
            a0 = MFMA(xh, *(const short8*)(WA + bo), a0);
            a1 = MFMA(xh, *(const short8*)(WB + bo), a1);
            const short8 bvh = *(const short8*)(WvH + bo);
            const short8 bvl = *(const short8*)(WvL + bo);
            av = MFMA(xh, bvh, av);
            av = MFMA(xh, bvl, av);
            av = MFMA(xl8, bvh, av);
        }
    }
    // ---- phase 2: convert this wave's acc -> Thi/Tlov (no cross-wave sums)
    {
        const int p = (w < 2) ? 0 : 1;
        const int colA = p * 64 + ntA * 16 + lr;
        const int colB = colA + 16;
        const int colV = 128 + w * 16 + lr;
#pragma unroll
        for (int i = 0; i < 4; i++) {
            const int row = lk * 4 + i;
            Thi[row * 200 + colA] = f2bf(a0[i]);
            Thi[row * 200 + colB] = f2bf(a1[i]);
            const short hv = f2bf(av[i]);
            Thi[row * 200 + colV] = hv;
            Tlov[row * 72 + w * 16 + lr] = f2bf(av[i] - bf2f(hv));
        }
    }
    __syncthreads();
    // ---- phase 3: this wave's n-quarter
    const int n0 = w * 256;
    short8 tf[3][2];  // [path][ks] hi
    short8 tfl[2];    // [ks] v-lo
#pragma unroll
    for (int ks = 0; ks < 2; ks++) {
#pragma unroll
        for (int p = 0; p < 3; p++)
            tf[p][ks] = *(const short8*)(Thi + lr * 200 + p * 64 + ks * 32 + lk * 8);
        tfl[ks] = *(const short8*)(Tlov + lr * 72 + ks * 32 + lk * 8);
    }
    const int bb = mb >> 11, mt = mb & (NT - 1);
#pragma unroll 2
    for (int nt = 0; nt < 16; nt++) {
        const int n = n0 + nt * 16 + lr;
        const size_t ub = (size_t)n * NR;
        short8 uq[2], uk[2], uvh[2], uvl[2];
#pragma unroll
        for (int ks = 0; ks < 2; ks++) {
            const size_t uo = ub + ks * 32 + lk * 8;
            uq[ks] = *(const short8*)(qUh + uo);
            uk[ks] = *(const short8*)(kUh + uo);
            uvh[ks] = *(const short8*)(vUh + uo);
            uvl[ks] = *(const short8*)(vUl + uo);
        }
        f32x4 aq = 0.0f, ak = 0.0f, avv = 0.0f;
#pragma unroll
        for (int ks = 0; ks < 2; ks++) {
            aq = MFMA(uq[ks], tf[0][ks], aq);  // swapped: lane->m, reg->n
            ak = MFMA(uk[ks], tf[1][ks], ak);
            avv = MFMA(tf[2][ks], uvh[ks], avv);  // unswapped: lane->n, reg->m
            avv = MFMA(tf[2][ks], uvl[ks], avv);
            avv = MFMA(tfl[ks], uvh[ks], avv);
        }
        // q,k: [B,H,T,D], lane row tt, regs run along dd -> packed 8B
        const int tt = mt + lr;
        const int nq = n0 + nt * 16 + lk * 4;
        const int hhq = nq >> 6, ddq = nq & 63;
        short4v pq, pk;
#pragma unroll
        for (int i = 0; i < 4; i++) { pq[i] = f2bf(aq[i]); pk[i] = f2bf(ak[i]); }
        *(short4v*)(qb + ((size_t)(bb * NH + hhq) * NT + tt) * ND + ddq) = pq;
        *(short4v*)(kb + ((size_t)(bb * NH + hhq) * NT + tt) * ND + ddq) = pk;
        // v: [B,H,D,T], lane col n -> (hh,dd), regs run along tt -> packed 8B
        const int hhv = n >> 6, ddv = n & 63;
        const int tv = mt + lk * 4;
        short4v pv;
#pragma unroll
        for (int i = 0; i < 4; i++) pv[i] = f2bf(avv[i]);
        *(short4v*)(vtb + ((size_t)(bb * NH + hhv) * ND + ddv) * NT + tv) = pv;
    }
}

// ---- fused c-path: y -> ty -> out. 512 blocks x 16 rows, staged Y windows.
__global__ __launch_bounds__(256) void k_cout(const short* __restrict__ Yb,
                                              const short* __restrict__ Whi, const short* __restrict__ Wlo,
                                              float* __restrict__ Out) {
    __shared__ __align__(16) char Yl[2][8192];  // [16 rows][256 bf16] per buf, swizzled
    __shared__ __align__(16) short tyhi[16 * 72];
    __shared__ __align__(16) short tylo[16 * 72];
    const int tid = threadIdx.x;
    const int w = tid >> 6, l = tid & 63;
    const int lr = l & 15, lk = l >> 4;
    const int mb = blockIdx.x * 16;
    const short* cVh = Whi + 3 * 65536;
    const short* cVl = Wlo + 3 * 65536;
    const short* cUh = Whi + 7 * 65536;
    const short* cUl = Wlo + 7 * 65536;

    auto stageY = [&](int buf, int win) {
#pragma unroll
        for (int i = 0; i < 2; i++) {
            const int L = (w * 2 + i) * 64 + l;
            const int r = L >> 5, lc = L & 31;
            const int c16 = lc ^ r;
            const short* g = Yb + (size_t)(mb + r) * NC + win * 256 + c16 * 8;
            gll16(g, Yl[buf] + (w * 2 + i) * 1024);
        }
    };

    // phase 1: ty tile w (2-term), full K, Y frags from swizzled LDS
    const short* WH = cVh + (size_t)(w * 16 + lr) * NC;
    const short* WL = cVl + (size_t)(w * 16 + lr) * NC;
    f32x4 acc = 0.0f;
    stageY(0, 0);
    for (int win = 0; win < 4; ++win) {
        const int buf = win & 1;
        __syncthreads();
        if (win < 3) stageY(buf ^ 1, win + 1);
        const char* YB = Yl[buf];
#pragma unroll
        for (int kk = 0; kk < 8; ++kk) {
            const int c16 = kk * 4 + lk;
            const short8 ah = *(const short8*)(YB + lr * 512 + ((c16 ^ lr) << 4));
            const int bo = win * 256 + kk * 32 + lk * 8;
            acc = MFMA(ah, *(const short8*)(WH + bo), acc);
            acc = MFMA(ah, *(const short8*)(WL + bo), acc);
        }
    }
    // phase 2: convert own tile -> tyhi/tylo
#pragma unroll
    for (int i = 0; i < 4; i++) {
        const int row = lk * 4 + i;
        const short h = f2bf(acc[i]);
        tyhi[row * 72 + w * 16 + lr] = h;
        tylo[row * 72 + w * 16 + lr] = f2bf(acc[i] - bf2f(h));
    }
    __syncthreads();
    // phase 3: out = ty @ cU^T (3-term), swapped MFMA -> float4 stores
    const int n0 = w * 256;
    short8 th[2], tl[2];
#pragma unroll
    for (int ks = 0; ks < 2; ks++) {
        th[ks] = *(const short8*)(tyhi + lr * 72 + ks * 32 + lk * 8);
        tl[ks] = *(const short8*)(tylo + lr * 72 + ks * 32 + lk * 8);
    }
#pragma unroll 2
    for (int nt = 0; nt < 16; nt++) {
        const size_t ub = (size_t)(n0 + nt * 16 + lr) * NR;
        short8 uh[2], ul[2];
#pragma unroll
        for (int ks = 0; ks < 2; ks++) {
            uh[ks] = *(const short8*)(cUh + ub + ks * 32 + lk * 8);
            ul[ks] = *(const short8*)(cUl + ub + ks * 32 + lk * 8);
        }
        f32x4 a = 0.0f;
#pragma unroll
        for (int ks = 0; ks < 2; ks++) {
            a = MFMA(uh[ks], th[ks], a);
            a = MFMA(ul[ks], th[ks], a);
            a = MFMA(uh[ks], tl[ks], a);
        }
        const int mm = mb + lr;
        const int n = n0 + nt * 16 + lk * 4;
        *(float4v*)(Out + (size_t)mm * NC + n) = *(float4v*)&a;
    }
}

// swizzled LDS fragment read: tile [64][64] bf16, row stride 128B, byte ^ (row&7)<<4
__device__ __forceinline__ short8 lds_frag(const short* base, int row, int cb) {
    return *(const short8*)((const char*)base + (((row << 7) + cb) ^ ((row & 7) << 4)));
}

// ---- causal flash attention (unchanged from R7). grid (16, B*H) XCD-swizzled.
__global__ __launch_bounds__(256, 4) void k_attn(const short* __restrict__ Qm,
                                                 const short* __restrict__ Km,
                                                 const short* __restrict__ Vt,
                                                 short* __restrict__ Y) {
    __shared__ __align__(16) short Kl[2][64 * 64];  // 16 KB dbuf, swizzled layout
    __shared__ __align__(16) short Vl[2][64 * 64];  // 16 KB
    __shared__ __align__(16) short Pl[4 * 1024];    // per-wave 16x64 P tile, swizzled
    const int tid = threadIdx.x;
    const int w = tid >> 6, l = tid & 63;
    const int lr = l & 15, lk = l >> 4;
    // bijective XCD-chunk swizzle: each XCD gets 8 complete bh's (K/V L2-resident)
    const int lin = blockIdx.y * 16 + blockIdx.x;
    const int nl = (lin & 7) * 128 + (lin >> 3);
    const int j = nl & 15;
    const int bh = nl >> 4;
    const int ntile = 32 - j;
    const int qA = 64 * j + w * 16;
    const int qB = (NT - 64 * (j + 1)) + w * 16;
    const int qrel = w * 16 + lr;  // diag-tile mask threshold (same for A and B)

    const short* Kb = Km + (size_t)bh * NT * ND;
    const short* Vb = Vt + (size_t)bh * ND * NT;

    short8 qfA[2], qfB[2];
#pragma unroll
    for (int ks = 0; ks < 2; ks++) {
        qfA[ks] = *(const short8*)(Qm + ((size_t)bh * NT + qA + lr) * ND + ks * 32 + lk * 8);
        qfB[ks] = *(const short8*)(Qm + ((size_t)bh * NT + qB + lr) * ND + ks * 32 + lk * 8);
    }

    const int grow8 = w * 8 + (l >> 3);                   // row within 32-row chunk
    const int gcolb = (((l & 7) ^ ((l >> 3) & 7)) << 4);  // byte col within row
    auto stage = [&](int buf, int kv0) {
        const char* kp = (const char*)Kb + (((size_t)(kv0 + grow8)) << 7) + gcolb;
        const char* vp = (const char*)Vb + (size_t)grow8 * (NT * 2) + kv0 * 2 + gcolb;
        char* kl = (char*)Kl[buf] + w * 1024;
        char* vl = (char*)Vl[buf] + w * 1024;
        gll16(kp, kl);
        gll16(kp + (32 << 7), kl + 4096);
        gll16(vp, vl);
        gll16(vp + (size_t)32 * NT * 2, vl + 4096);
    };

    f32x4 lsA = 0.0f, lsB = 0.0f;  // per-lane softmax-denominator partials
    f32x4 oA[4], oB[4];
#pragma unroll
    for (int dt = 0; dt < 4; dt++) { oA[dt] = 0.0f; oB[dt] = 0.0f; }

    char* plb = (char*)Pl + w * 2048;

    auto compute = [&](const short8* qf, f32x4& ls, f32x4* o,
                       const short* KlB, const short* VlB, bool diag) {
        // S^T - 16 via C-init: lane holds S[kv=nt*16+lk*4+i][q0+lr] - 16
        f32x4 sa[4];
#pragma unroll
        for (int nt = 0; nt < 4; nt++) sa[nt] = -16.0f;
        __builtin_amdgcn_s_setprio(1);
#pragma unroll
        for (int ks = 0; ks < 2; ks++) {
#pragma unroll
            for (int nt = 0; nt < 4; nt++) {
                const short8 kf = lds_frag(KlB, nt * 16 + lr, ks * 64 + lk * 16);
                sa[nt] = MFMA(kf, qf[ks], sa[nt]);
            }
        }
        __builtin_amdgcn_s_setprio(0);
        if (diag) {
#pragma unroll
            for (int nt = 0; nt < 4; nt++) {
                const int kvb = nt * 16 + lk * 4;
#pragma unroll
                for (int i = 0; i < 4; i++)
                    if (kvb + i > qrel) sa[nt][i] = -1e30f;
            }
        }
        f32x4 sv[4];
#pragma unroll
        for (int nt = 0; nt < 4; nt++) {
#pragma unroll
            for (int i = 0; i < 4; i++) sv[nt][i] = exp2_(sa[nt][i]);
            ls += sv[nt];
        }
        // P^T -> per-wave LDS (b64 writes), then B-frag reads (b128)
#pragma unroll
        for (int nt = 0; nt < 4; nt++) {
            short4v pk;
#pragma unroll
            for (int i = 0; i < 4; i++) pk[i] = f2bf(sv[nt][i]);
            *(short4v*)(plb + (((lr << 7) + ((nt * 16 + lk * 4) << 1)) ^ ((lr & 7) << 4))) = pk;
        }
        const short8 pb0 = *(const short8*)(plb + (((lr << 7) + ((lk * 8) << 1)) ^ ((lr & 7) << 4)));
        const short8 pb1 = *(const short8*)(plb + (((lr << 7) + ((32 + lk * 8) << 1)) ^ ((lr & 7) << 4)));
        // O^T += V^T . P : lane holds O[d=dt*16+lk*4+i][q0+lr]
        __builtin_amdgcn_s_setprio(1);
#pragma unroll
        for (int ks = 0; ks < 2; ks++) {
            const short8 pb = ks ? pb1 : pb0;
#pragma unroll
            for (int dt = 0; dt < 4; dt++) {
                const short8 vf = lds_frag(VlB, dt * 16 + lr, ks * 64 + lk * 16);
                o[dt] = MFMA(vf, pb, o[dt]);
            }
        }
        __builtin_amdgcn_s_setprio(0);
    };

    stage(0, 0);  // tile 0 -> buf 0
    for (int it = 0; it < ntile; ++it) {
        const int buf = it & 1;
        __syncthreads();  // drains this tile's global_load_lds (vmcnt) + syncs
        if (it + 1 < ntile) stage(buf ^ 1, (it + 1) * 64);  // overlaps compute below
        const short* KlB = Kl[buf];
        const short* VlB = Vl[buf];
        if (it <= j) compute(qfA, lsA, oA, KlB, VlB, it == j);
        compute(qfB, lsB, oB, KlB, VlB, it == ntile - 1);
    }

    // final l reduction: row sum lives across the 4 lanes sharing lr
    float lA = (lsA[0] + lsA[1]) + (lsA[2] + lsA[3]);
    float lB = (lsB[0] + lsB[1]) + (lsB[2] + lsB[3]);
    lA += __shfl_xor(lA, 16);
    lA += __shfl_xor(lA, 32);
    lB += __shfl_xor(lB, 16);
    lB += __shfl_xor(lB, 32);

    const int b = bh >> 4, h = bh & 15;
    const float invA = 1.0f / lA, invB = 1.0f / lB;
    short* ypA = Y + ((size_t)b * NT + (qA + lr)) * NC + h * ND;
    short* ypB = Y + ((size_t)b * NT + (qB + lr)) * NC + h * ND;
#pragma unroll
    for (int dt = 0; dt < 4; dt++) {
        short4v ya, yb2;
#pragma unroll
        for (int i = 0; i < 4; i++) {
            ya[i] = f2bf(oA[dt][i] * invA);
            yb2[i] = f2bf(oB[dt][i] * invB);
        }
        *(short4v*)(ypA + dt * 16 + lk * 4) = ya;
        *(short4v*)(ypB + dt * 16 + lk * 4) = yb2;
    }
}

extern "C" void kernel_launch(void* const* d_in, const int* in_sizes, int n_in,
                              void* d_out, int out_size, void* d_ws, size_t ws_size,
                              hipStream_t stream) {
    const float* x = (const float*)d_in[0];
    const float* qU = (const float*)d_in[1];
    const float* qV = (const float*)d_in[2];
    const float* kU = (const float*)d_in[3];
    const float* kV = (const float*)d_in[4];
    const float* vU = (const float*)d_in[5];
    const float* vV = (const float*)d_in[6];
    const float* cU = (const float*)d_in[7];
    const float* cV = (const float*)d_in[8];
    float* out = (float*)d_out;

    char* ws = (char*)d_ws;
    size_t off = 0;
    auto take = [&](size_t bytes) {
        char* p = ws + off;
        off += (bytes + 255) & ~(size_t)255;
        return p;
    };
    short* Whi = (short*)take(8 * 65536 * 2);
    short* Wlo = (short*)take(8 * 65536 * 2);
    short* qb = (short*)take((size_t)NM * NC * 2);
    short* kb = (short*)take((size_t)NM * NC * 2);
    short* vtb = (short*)take((size_t)NM * NC * 2);
    short* yb = (short*)take((size_t)NM * NC * 2);

    k_prep<<<dim3(256, 8), 256, 0, stream>>>(qV, kV, vV, cV, qU, kU, vU, cU, Whi, Wlo);
    k_qkv<<<512, 256, 0, stream>>>(x, Whi, Wlo, qb, kb, vtb);
    k_attn<<<dim3(16, NB * NH), 256, 0, stream>>>(qb, kb, vtb, yb);
    k_cout<<<512, 256, 0, stream>>>(yb, Whi, Wlo, out);
}